// Round 11
// baseline (232.929 us; speedup 1.0000x reference)
//
#include <hip/hip_runtime.h>
#include <hip/hip_bf16.h>

typedef __bf16 bf16;
typedef __attribute__((ext_vector_type(8))) __bf16 bf16x8;
typedef __attribute__((ext_vector_type(4))) __bf16 bf16x4;
typedef __attribute__((ext_vector_type(4))) float f32x4;

#define TSEQ 2048
#define DMODEL 1024
#define NHEAD 16
#define DKH 64
#define BATCH 2
#define NQKV 3072
#define PSTR 72   // flash P-tile LDS stride

// async global->LDS, 16B per lane; LDS dest = wave-uniform base + lane*16
typedef __attribute__((address_space(1))) const void gv_t;
typedef __attribute__((address_space(3))) void sv_t;
__device__ __forceinline__ void gll16(const bf16* g, bf16* s) {
    __builtin_amdgcn_global_load_lds((gv_t*)g, (sv_t*)s, 16, 0, 0);
}
// s_waitcnt vmcnt(0) only — compiler does NOT associate pending LDS-DMA with
// s_barrier (round-6 race); keep this before each barrier after gll.
__device__ __forceinline__ void wait_vm0() {
    __builtin_amdgcn_s_waitcnt(0x0F70);
}

// ------------------------------------------------- fused prologue (1 launch)
__global__ __launch_bounds__(256) void prologue(
    const float* __restrict__ x,
    const float* __restrict__ W0, const float* __restrict__ W1,
    const float* __restrict__ W2, const float* __restrict__ W3,
    const float* __restrict__ bq, const float* __restrict__ bk,
    const float* __restrict__ bv,
    bf16* __restrict__ xb, bf16* __restrict__ WT, float* __restrict__ wsBias)
{
    __shared__ float t[32][33];
    const int bid = blockIdx.x, tid = threadIdx.x;
    if (bid < 4096) {                       // W transpose + cast
        const int mz = bid >> 10, tt = bid & 1023;
        const float* W = mz == 0 ? W0 : mz == 1 ? W1 : mz == 2 ? W2 : W3;
        bf16* T = WT + (size_t)mz * DMODEL * DMODEL;
        const int bx = (tt & 31) * 32, by = (tt >> 5) * 32;
        const int tx = tid & 31, ty = tid >> 5;
#pragma unroll
        for (int i = 0; i < 4; ++i)
            t[ty + i * 8][tx] = W[(size_t)(by + ty + i * 8) * DMODEL + bx + tx];
        __syncthreads();
#pragma unroll
        for (int i = 0; i < 4; ++i)
            T[(size_t)(bx + ty + i * 8) * DMODEL + by + tx] = (bf16)t[tx][ty + i * 8];
    } else if (bid < 8192) {                // x fp32 -> bf16
        int i = ((bid - 4096) * 256 + tid) * 4;
        f32x4 v = *(const f32x4*)(x + i);
        bf16x4 o;
#pragma unroll
        for (int j = 0; j < 4; ++j) o[j] = (bf16)v[j];
        *(bf16x4*)(xb + i) = o;
    } else {                                // qkv bias concat
        int i = (bid - 8192) * 256 + tid;   // 0..3071
        wsBias[i] = i < 1024 ? bq[i] : i < 2048 ? bk[i - 1024] : bv[i - 2048];
    }
}

// ---------------------------------------------------------------- GEMM
// Single-buffered m97 K-loop + XOR-swizzled LDS (4-way max conflicts, was
// 8-way). Split-K via blockIdx.z: z=0 writes C0, z=1 writes C1 (no bias —
// reduce adds it) unless ZSPLIT==1 (then bias applied here).
// V-mode (Vout!=null, n0>=2048): tile written as V^T[b][h*64+d][t].
template <typename OutT>
__global__ __launch_bounds__(256) void gemm_bias_kernel(
    const bf16* __restrict__ A, const bf16* __restrict__ BT,
    const float* __restrict__ bias, OutT* __restrict__ C0,
    OutT* __restrict__ C1, int ldc, bf16* __restrict__ Vout, int ksteps)
{
    __shared__ bf16 As[128 * 32];
    __shared__ bf16 Bs[128 * 32];
    const int tid = threadIdx.x;
    const int ln = tid & 63, wave = tid >> 6;
    const int wm = wave >> 1, wn = wave & 1;
    const int lr = ln & 15, quad = ln >> 4;
    const int m0 = blockIdx.y * 128, n0 = blockIdx.x * 128;
    const int k0 = blockIdx.z * ksteps * 32;
    OutT* C = blockIdx.z == 0 ? C0 : C1;

    f32x4 acc[4][4] = {};

    const int grow = wave * 32 + (ln >> 2);
    const int gch = (ln & 3) ^ ((ln >> 2) & 3);   // global-side swizzle
    const bf16* Ag = A + (size_t)(m0 + grow) * DMODEL + gch * 8;
    const bf16* Bg = BT + (size_t)(n0 + grow) * DMODEL + gch * 8;
    bf16* AsW = As + wave * 1024;
    bf16* BsW = Bs + wave * 1024;
    const int rsw = (lr & 3);                     // read-side row&3

    for (int kt = 0; kt < ksteps; ++kt) {
        const int kk = k0 + kt * 32;
        gll16(Ag + kk, AsW);
        gll16(Ag + (size_t)16 * DMODEL + kk, AsW + 512);
        gll16(Bg + kk, BsW);
        gll16(Bg + (size_t)16 * DMODEL + kk, BsW + 512);
        wait_vm0();
        __syncthreads();
        bf16x8 af[4], bfr[4];
#pragma unroll
        for (int i = 0; i < 4; ++i)
            af[i] = *(const bf16x8*)(As + (wm * 64 + i * 16 + lr) * 32 +
                                     ((quad ^ rsw) * 8));
#pragma unroll
        for (int j = 0; j < 4; ++j)
            bfr[j] = *(const bf16x8*)(Bs + (wn * 64 + j * 16 + lr) * 32 +
                                      ((quad ^ rsw) * 8));
#pragma unroll
        for (int i = 0; i < 4; ++i)
#pragma unroll
            for (int j = 0; j < 4; ++j)
                acc[i][j] = __builtin_amdgcn_mfma_f32_16x16x32_bf16(
                    af[i], bfr[j], acc[i][j], 0, 0, 0);
        __syncthreads();
    }

    if (Vout != nullptr && n0 >= 2048) {
        const int bb = m0 >> 11;
        const int tb_ = (m0 & (TSEQ - 1)) + wm * 64;
#pragma unroll
        for (int j = 0; j < 4; ++j) {
            int n = n0 + wn * 64 + j * 16 + lr;
            int hd = n - 2048;
            float bv = bias[n];
            bf16* vrow = Vout + ((size_t)(bb * DMODEL + hd)) * TSEQ;
#pragma unroll
            for (int i = 0; i < 4; ++i) {
                int t = tb_ + i * 16 + quad * 4;
                bf16x4 v4;
#pragma unroll
                for (int r = 0; r < 4; ++r) v4[r] = (bf16)(acc[i][j][r] + bv);
                *(bf16x4*)(vrow + t) = v4;
            }
        }
    } else {
#pragma unroll
        for (int j = 0; j < 4; ++j) {
            int n = n0 + wn * 64 + j * 16 + lr;
            float bv = bias ? bias[n] : 0.f;
#pragma unroll
            for (int i = 0; i < 4; ++i) {
                int mb = m0 + wm * 64 + i * 16 + quad * 4;
#pragma unroll
                for (int r = 0; r < 4; ++r)
                    C[(size_t)(mb + r) * ldc + n] = (OutT)(acc[i][j][r] + bv);
            }
        }
    }
}

// ------------------------------------------------------- split-K reduce
__global__ __launch_bounds__(256) void reduce_out(
    const float* __restrict__ P1, const float* __restrict__ bias,
    float* __restrict__ out)
{
    int i = (blockIdx.x * 256 + threadIdx.x) * 4;
    f32x4 a = *(const f32x4*)(out + i);
    f32x4 b = *(const f32x4*)(P1 + i);
    f32x4 bi = *(const f32x4*)(bias + (i & (DMODEL - 1)));
    f32x4 r = a + b + bi;
    *(f32x4*)(out + i) = r;
}

// ---------------------------------------------------------------- flash attn
template <bool MASK>
__device__ __forceinline__ void attn_chunk(
    int kc, int q0w, int lr, int quad,
    const bf16* __restrict__ KsB, const bf16* __restrict__ VsB,
    bf16* __restrict__ Pw,
    const bf16x8 qb[2], f32x4 oacc[4], float& lrow)
{
    const int sw = lr & 7;
    bf16x8 kb[4][2];
#pragma unroll
    for (int kt = 0; kt < 4; ++kt)
#pragma unroll
        for (int kk = 0; kk < 2; ++kk)
            kb[kt][kk] = *(const bf16x8*)(KsB + (kt * 16 + lr) * 64 +
                                          (((kk * 4 + quad) ^ sw) * 8));
    f32x4 st[4] = {};
#pragma unroll
    for (int kt = 0; kt < 4; ++kt)
#pragma unroll
        for (int kk = 0; kk < 2; ++kk)
            st[kt] = __builtin_amdgcn_mfma_f32_16x16x32_bf16(
                kb[kt][kk], qb[kk], st[kt], 0, 0, 0);

    const float scale2 = 0.18033688f; // 0.125 * log2(e)
    const int q = q0w + lr;
    float rs = 0.f;
#pragma unroll
    for (int kt = 0; kt < 4; ++kt) {
        bf16x4 p4;
#pragma unroll
        for (int r = 0; r < 4; ++r) {
            float p = exp2f(fmaf(st[kt][r], scale2, -24.0f));
            if (MASK && (kc + kt * 16 + quad * 4 + r > q)) p = 0.f;
            rs += p;
            p4[r] = (bf16)p;
        }
        *(bf16x4*)(Pw + lr * PSTR + kt * 16 + quad * 4) = p4;
    }
    rs += __shfl_xor(rs, 16);
    rs += __shfl_xor(rs, 32);
    lrow += rs;

#pragma unroll
    for (int kk = 0; kk < 2; ++kk) {
        bf16x8 pa = *(const bf16x8*)(Pw + lr * PSTR + kk * 32 + quad * 8);
#pragma unroll
        for (int dt = 0; dt < 4; ++dt) {
            bf16x8 vb = *(const bf16x8*)(VsB + (dt * 16 + lr) * 64 +
                                         (((kk * 4 + quad) ^ sw) * 8));
            oacc[dt] = __builtin_amdgcn_mfma_f32_16x16x32_bf16(
                pa, vb, oacc[dt], 0, 0, 0);
        }
    }
}

__global__ __launch_bounds__(512) void flash_attn(
    const bf16* __restrict__ QKV, const bf16* __restrict__ VT,
    bf16* __restrict__ O)
{
    __shared__ bf16 Ks[2][64 * 64];
    __shared__ bf16 Vs[2][64 * 64];
    __shared__ bf16 Pl[8][16 * PSTR];
    const int tid = threadIdx.x;
    const int ln = tid & 63, w = tid >> 6;
    const int lr = ln & 15, quad = ln >> 4;
    const int h = blockIdx.y, b = blockIdx.z;

    int xb = blockIdx.x;
    if ((h ^ b) & 1) xb = (TSEQ / 128 - 1) - xb;
    const int q0 = xb * 128;
    const int q0w = q0 + w * 16;
    bf16* Pw = Pl[w];

    const bf16* Qb = QKV + (size_t)b * TSEQ * NQKV + h * DKH;
    const bf16* Kb = Qb + 1024;
    const bf16* VTb = VT + (size_t)(b * NHEAD + h) * DKH * TSEQ;

    const int srow = (w & 3) * 16 + (ln >> 3);
    const int scol = ((ln & 7) ^ ((ln >> 3) & 7)) * 8;
    const bool stK = (w < 4);

    auto stage = [&](int buf, int kc) {
        if (stK) {
            const bf16* g = Kb + (size_t)(kc + srow) * NQKV + scol;
            bf16* s = &Ks[buf][(w & 3) * 16 * 64];
#pragma unroll
            for (int l = 0; l < 2; ++l)
                gll16(g + (size_t)(l * 8) * NQKV, s + l * 8 * 64);
        } else {
            const bf16* g = VTb + (size_t)srow * TSEQ + kc + scol;
            bf16* s = &Vs[buf][(w & 3) * 16 * 64];
#pragma unroll
            for (int l = 0; l < 2; ++l)
                gll16(g + (size_t)(l * 8) * TSEQ, s + l * 8 * 64);
        }
    };

    bf16x8 qb[2];
#pragma unroll
    for (int kk = 0; kk < 2; ++kk)
        qb[kk] = *(const bf16x8*)(Qb + (size_t)(q0w + lr) * NQKV +
                                  kk * 32 + quad * 8);

    f32x4 oacc[4] = {};
    float lrow = 0.f;

    const int nch = (q0 + 128) >> 6;
    stage(0, 0);
    wait_vm0();
    __syncthreads();
    for (int c = 0; c < nch; ++c) {
        if (c + 1 < nch) stage((c + 1) & 1, (c + 1) * 64);
        const int kc = c * 64;
        if (kc <= q0w + 15) {
            if (kc + 63 <= q0w)
                attn_chunk<false>(kc, q0w, lr, quad, Ks[c & 1], Vs[c & 1], Pw,
                                  qb, oacc, lrow);
            else
                attn_chunk<true>(kc, q0w, lr, quad, Ks[c & 1], Vs[c & 1], Pw,
                                 qb, oacc, lrow);
        }
        wait_vm0();
        __syncthreads();
    }

#pragma unroll
    for (int r = 0; r < 4; ++r) {
        float inv = 1.0f / __shfl(lrow, quad * 4 + r);
        int row = q0w + quad * 4 + r;
#pragma unroll
        for (int dt = 0; dt < 4; ++dt)
            O[(size_t)(b * TSEQ + row) * DMODEL + h * DKH + dt * 16 + lr] =
                (bf16)(oacc[dt][r] * inv);
    }
}

// ---------------------------------------------------------------- launch
extern "C" void kernel_launch(void* const* d_in, const int* in_sizes, int n_in,
                              void* d_out, int out_size, void* d_ws, size_t ws_size,
                              hipStream_t stream)
{
    const float* x  = (const float*)d_in[0];
    const float* Wq = (const float*)d_in[2];
    const float* bq = (const float*)d_in[3];
    const float* Wk = (const float*)d_in[4];
    const float* bk = (const float*)d_in[5];
    const float* Wv = (const float*)d_in[6];
    const float* bv = (const float*)d_in[7];
    const float* Wo = (const float*)d_in[8];
    const float* bo = (const float*)d_in[9];

    char* ws = (char*)d_ws;
    bf16* xb   = (bf16*)(ws);                   // 8 MB
    bf16* QKV  = (bf16*)(ws + (8u  << 20));     // 24 MB (Q,K live; dead after flash)
    bf16* VT   = (bf16*)(ws + (32u << 20));     // 8 MB V^T (GEMM-written)
    bf16* O    = (bf16*)(ws + (40u << 20));     // 8 MB (hosts QKV bias pre-flash)
    bf16* WT   = (bf16*)(ws + (48u << 20));     // 8 MB
    float* wsBias = (float*)O;                  // 12 KB; dead once flash writes O
    float* P1  = (float*)QKV;                   // 16 MB split-K partial (QKV dead)

    prologue<<<8204, 256, 0, stream>>>(x, Wq, Wk, Wv, Wo, bq, bk, bv,
                                       xb, WT, wsBias);

    // QKV projection; V columns go straight to VT (transposed)
    gemm_bias_kernel<bf16><<<dim3(NQKV / 128, 32, 1), 256, 0, stream>>>(
        xb, WT, wsBias, QKV, QKV, NQKV, VT, DMODEL / 32);

    flash_attn<<<dim3(TSEQ / 128, NHEAD, BATCH), 512, 0, stream>>>(QKV, VT, O);

    // out projection, split-K=2: z=0 -> d_out (partial), z=1 -> P1; no bias
    gemm_bias_kernel<float><<<dim3(DMODEL / 128, 32, 2), 256, 0, stream>>>(
        O, WT + 3u * (1u << 20), nullptr, (float*)d_out, P1, DMODEL, nullptr,
        DMODEL / 64);

    reduce_out<<<(BATCH * TSEQ * DMODEL) / 1024, 256, 0, stream>>>(
        P1, bo, (float*)d_out);
}

// Round 12
// 232.262 us; speedup vs baseline: 1.0029x; 1.0029x over previous
//
#include <hip/hip_runtime.h>
#include <hip/hip_bf16.h>

typedef __bf16 bf16;
typedef __attribute__((ext_vector_type(8))) __bf16 bf16x8;
typedef __attribute__((ext_vector_type(4))) __bf16 bf16x4;
typedef __attribute__((ext_vector_type(4))) float f32x4;

#define TSEQ 2048
#define DMODEL 1024
#define NHEAD 16
#define DKH 64
#define BATCH 2
#define NQKV 3072
#define PSTR 72   // flash P-tile LDS stride

// async global->LDS, 16B per lane; LDS dest = wave-uniform base + lane*16
typedef __attribute__((address_space(1))) const void gv_t;
typedef __attribute__((address_space(3))) void sv_t;
__device__ __forceinline__ void gll16(const bf16* g, bf16* s) {
    __builtin_amdgcn_global_load_lds((gv_t*)g, (sv_t*)s, 16, 0, 0);
}
// s_waitcnt vmcnt(N) only (expcnt/lgkmcnt untouched). N=0 drains all;
// N=8 with 12 in flight retires the oldest 4 (in-order retirement, m135).
// Compiler does NOT associate pending LDS-DMA with s_barrier (round-6 race):
// always wait explicitly before the barrier that publishes staged data.
template <int N>
__device__ __forceinline__ void wait_vm() {
    __builtin_amdgcn_s_waitcnt(0x0F70 | N);
}

// ------------------------------------------------- fused prologue (1 launch)
__global__ __launch_bounds__(256) void prologue(
    const float* __restrict__ x,
    const float* __restrict__ W0, const float* __restrict__ W1,
    const float* __restrict__ W2, const float* __restrict__ W3,
    const float* __restrict__ bq, const float* __restrict__ bk,
    const float* __restrict__ bv,
    bf16* __restrict__ xb, bf16* __restrict__ WT, float* __restrict__ wsBias)
{
    __shared__ float t[32][33];
    const int bid = blockIdx.x, tid = threadIdx.x;
    if (bid < 4096) {                       // W transpose + cast
        const int mz = bid >> 10, tt = bid & 1023;
        const float* W = mz == 0 ? W0 : mz == 1 ? W1 : mz == 2 ? W2 : W3;
        bf16* T = WT + (size_t)mz * DMODEL * DMODEL;
        const int bx = (tt & 31) * 32, by = (tt >> 5) * 32;
        const int tx = tid & 31, ty = tid >> 5;
#pragma unroll
        for (int i = 0; i < 4; ++i)
            t[ty + i * 8][tx] = W[(size_t)(by + ty + i * 8) * DMODEL + bx + tx];
        __syncthreads();
#pragma unroll
        for (int i = 0; i < 4; ++i)
            T[(size_t)(bx + ty + i * 8) * DMODEL + by + tx] = (bf16)t[tx][ty + i * 8];
    } else if (bid < 8192) {                // x fp32 -> bf16
        int i = ((bid - 4096) * 256 + tid) * 4;
        f32x4 v = *(const f32x4*)(x + i);
        bf16x4 o;
#pragma unroll
        for (int j = 0; j < 4; ++j) o[j] = (bf16)v[j];
        *(bf16x4*)(xb + i) = o;
    } else {                                // qkv bias concat
        int i = (bid - 8192) * 256 + tid;   // 0..3071
        wsBias[i] = i < 1024 ? bq[i] : i < 2048 ? bk[i - 1024] : bv[i - 2048];
    }
}

// ---------------------------------------------------------------- GEMM
// Depth-3 pipelined K-loop: 4 LDS buffers, prologue stages steps 0..2,
// iteration k waits vmcnt(8) (oldest step's 4 glls), one barrier, issues
// step k+3 into buf (k+3)&3 (safe: last read of that buf was iter k-1,
// ordered by this barrier), computes buf k&3. Prefetch gets ~3 steps of
// flight time -> staging latency hidden (the round-11 measured 1500 cyc/step
// chain was the exposed vmcnt(0) drain).
// V-mode (Vout!=null, n0>=2048): tile written as V^T[b][h*64+d][t].
template <typename OutT>
__global__ __launch_bounds__(256) void gemm_bias_kernel(
    const bf16* __restrict__ A, const bf16* __restrict__ BT,
    const float* __restrict__ bias, OutT* __restrict__ C, int ldc,
    bf16* __restrict__ Vout)
{
    __shared__ bf16 As[4][128 * 32];
    __shared__ bf16 Bs[4][128 * 32];
    const int tid = threadIdx.x;
    const int ln = tid & 63, wave = tid >> 6;
    const int wm = wave >> 1, wn = wave & 1;
    const int lr = ln & 15, quad = ln >> 4;
    const int m0 = blockIdx.y * 128, n0 = blockIdx.x * 128;

    f32x4 acc[4][4] = {};

    const int grow = wave * 32 + (ln >> 2);
    const int gcol = (ln & 3) * 8;
    const bf16* Ag = A + (size_t)(m0 + grow) * DMODEL + gcol;
    const bf16* Bg = BT + (size_t)(n0 + grow) * DMODEL + gcol;

    auto stage = [&](int buf, int kt) {
        const int kk = kt * 32;
        bf16* aw = &As[buf][wave * 1024];
        bf16* bw = &Bs[buf][wave * 1024];
        gll16(Ag + kk, aw);
        gll16(Ag + (size_t)16 * DMODEL + kk, aw + 512);
        gll16(Bg + kk, bw);
        gll16(Bg + (size_t)16 * DMODEL + kk, bw + 512);
    };

    auto compute = [&](int buf) {
        bf16x8 af[4], bfr[4];
#pragma unroll
        for (int i = 0; i < 4; ++i)
            af[i] = *(const bf16x8*)(&As[buf][(wm * 64 + i * 16 + lr) * 32 + quad * 8]);
#pragma unroll
        for (int j = 0; j < 4; ++j)
            bfr[j] = *(const bf16x8*)(&Bs[buf][(wn * 64 + j * 16 + lr) * 32 + quad * 8]);
#pragma unroll
        for (int i = 0; i < 4; ++i)
#pragma unroll
            for (int j = 0; j < 4; ++j)
                acc[i][j] = __builtin_amdgcn_mfma_f32_16x16x32_bf16(
                    af[i], bfr[j], acc[i][j], 0, 0, 0);
    };

    stage(0, 0); stage(1, 1); stage(2, 2);   // 12 glls in flight

    for (int k = 0; k < 29; ++k) {
        wait_vm<8>();          // oldest 4 (step k) landed
        __syncthreads();       // publish buf k&3; orders last reads of (k+3)&3
        stage((k + 3) & 3, k + 3);
        compute(k & 3);
    }
    wait_vm<8>(); __syncthreads(); compute(1);   // k=29 (in flight: 29,30,31)
    wait_vm<4>(); __syncthreads(); compute(2);   // k=30
    wait_vm<0>(); __syncthreads(); compute(3);   // k=31

    if (Vout != nullptr && n0 >= 2048) {
        const int bb = m0 >> 11;
        const int tb_ = (m0 & (TSEQ - 1)) + wm * 64;
#pragma unroll
        for (int j = 0; j < 4; ++j) {
            int n = n0 + wn * 64 + j * 16 + lr;
            int hd = n - 2048;
            float bv = bias[n];
            bf16* vrow = Vout + ((size_t)(bb * DMODEL + hd)) * TSEQ;
#pragma unroll
            for (int i = 0; i < 4; ++i) {
                int t = tb_ + i * 16 + quad * 4;
                bf16x4 v4;
#pragma unroll
                for (int r = 0; r < 4; ++r) v4[r] = (bf16)(acc[i][j][r] + bv);
                *(bf16x4*)(vrow + t) = v4;
            }
        }
    } else {
#pragma unroll
        for (int j = 0; j < 4; ++j) {
            int n = n0 + wn * 64 + j * 16 + lr;
            float bv = bias[n];
#pragma unroll
            for (int i = 0; i < 4; ++i) {
                int mb = m0 + wm * 64 + i * 16 + quad * 4;
#pragma unroll
                for (int r = 0; r < 4; ++r)
                    C[(size_t)(mb + r) * ldc + n] = (OutT)(acc[i][j][r] + bv);
            }
        }
    }
}

// ---------------------------------------------------------------- flash attn
// Round-8 config (proven 47.2 us): 8 waves x 16 q-rows = 128 rows/block.
// K/V 64-key tiles double-buffered via gll (XOR swizzle, stride 64), one
// barrier per chunk with explicit vmcnt drain. Fixed-max softmax (M=24,
// exp2 domain).
template <bool MASK>
__device__ __forceinline__ void attn_chunk(
    int kc, int q0w, int lr, int quad,
    const bf16* __restrict__ KsB, const bf16* __restrict__ VsB,
    bf16* __restrict__ Pw,
    const bf16x8 qb[2], f32x4 oacc[4], float& lrow)
{
    const int sw = lr & 7;
    bf16x8 kb[4][2];
#pragma unroll
    for (int kt = 0; kt < 4; ++kt)
#pragma unroll
        for (int kk = 0; kk < 2; ++kk)
            kb[kt][kk] = *(const bf16x8*)(KsB + (kt * 16 + lr) * 64 +
                                          (((kk * 4 + quad) ^ sw) * 8));
    f32x4 st[4] = {};
#pragma unroll
    for (int kt = 0; kt < 4; ++kt)
#pragma unroll
        for (int kk = 0; kk < 2; ++kk)
            st[kt] = __builtin_amdgcn_mfma_f32_16x16x32_bf16(
                kb[kt][kk], qb[kk], st[kt], 0, 0, 0);

    const float scale2 = 0.18033688f; // 0.125 * log2(e)
    const int q = q0w + lr;
    float rs = 0.f;
#pragma unroll
    for (int kt = 0; kt < 4; ++kt) {
        bf16x4 p4;
#pragma unroll
        for (int r = 0; r < 4; ++r) {
            float p = exp2f(fmaf(st[kt][r], scale2, -24.0f));
            if (MASK && (kc + kt * 16 + quad * 4 + r > q)) p = 0.f;
            rs += p;
            p4[r] = (bf16)p;
        }
        *(bf16x4*)(Pw + lr * PSTR + kt * 16 + quad * 4) = p4;
    }
    rs += __shfl_xor(rs, 16);
    rs += __shfl_xor(rs, 32);
    lrow += rs;

#pragma unroll
    for (int kk = 0; kk < 2; ++kk) {
        bf16x8 pa = *(const bf16x8*)(Pw + lr * PSTR + kk * 32 + quad * 8);
#pragma unroll
        for (int dt = 0; dt < 4; ++dt) {
            bf16x8 vb = *(const bf16x8*)(VsB + (dt * 16 + lr) * 64 +
                                         (((kk * 4 + quad) ^ sw) * 8));
            oacc[dt] = __builtin_amdgcn_mfma_f32_16x16x32_bf16(
                pa, vb, oacc[dt], 0, 0, 0);
        }
    }
}

__global__ __launch_bounds__(512) void flash_attn(
    const bf16* __restrict__ QKV, const bf16* __restrict__ VT,
    bf16* __restrict__ O)
{
    __shared__ bf16 Ks[2][64 * 64];
    __shared__ bf16 Vs[2][64 * 64];
    __shared__ bf16 Pl[8][16 * PSTR];
    const int tid = threadIdx.x;
    const int ln = tid & 63, w = tid >> 6;
    const int lr = ln & 15, quad = ln >> 4;
    const int h = blockIdx.y, b = blockIdx.z;

    int xb = blockIdx.x;
    if ((h ^ b) & 1) xb = (TSEQ / 128 - 1) - xb;
    const int q0 = xb * 128;
    const int q0w = q0 + w * 16;
    bf16* Pw = Pl[w];

    const bf16* Qb = QKV + (size_t)b * TSEQ * NQKV + h * DKH;
    const bf16* Kb = Qb + 1024;
    const bf16* VTb = VT + (size_t)(b * NHEAD + h) * DKH * TSEQ;

    const int srow = (w & 3) * 16 + (ln >> 3);
    const int scol = ((ln & 7) ^ ((ln >> 3) & 7)) * 8;
    const bool stK = (w < 4);

    auto stage = [&](int buf, int kc) {
        if (stK) {
            const bf16* g = Kb + (size_t)(kc + srow) * NQKV + scol;
            bf16* s = &Ks[buf][(w & 3) * 16 * 64];
#pragma unroll
            for (int l = 0; l < 2; ++l)
                gll16(g + (size_t)(l * 8) * NQKV, s + l * 8 * 64);
        } else {
            const bf16* g = VTb + (size_t)srow * TSEQ + kc + scol;
            bf16* s = &Vs[buf][(w & 3) * 16 * 64];
#pragma unroll
            for (int l = 0; l < 2; ++l)
                gll16(g + (size_t)(l * 8) * TSEQ, s + l * 8 * 64);
        }
    };

    bf16x8 qb[2];
#pragma unroll
    for (int kk = 0; kk < 2; ++kk)
        qb[kk] = *(const bf16x8*)(Qb + (size_t)(q0w + lr) * NQKV +
                                  kk * 32 + quad * 8);

    f32x4 oacc[4] = {};
    float lrow = 0.f;

    const int nch = (q0 + 128) >> 6;
    stage(0, 0);
    wait_vm<0>();
    __syncthreads();
    for (int c = 0; c < nch; ++c) {
        if (c + 1 < nch) stage((c + 1) & 1, (c + 1) * 64);
        const int kc = c * 64;
        if (kc <= q0w + 15) {
            if (kc + 63 <= q0w)
                attn_chunk<false>(kc, q0w, lr, quad, Ks[c & 1], Vs[c & 1], Pw,
                                  qb, oacc, lrow);
            else
                attn_chunk<true>(kc, q0w, lr, quad, Ks[c & 1], Vs[c & 1], Pw,
                                 qb, oacc, lrow);
        }
        wait_vm<0>();
        __syncthreads();
    }

#pragma unroll
    for (int r = 0; r < 4; ++r) {
        float inv = 1.0f / __shfl(lrow, quad * 4 + r);
        int row = q0w + quad * 4 + r;
#pragma unroll
        for (int dt = 0; dt < 4; ++dt)
            O[(size_t)(b * TSEQ + row) * DMODEL + h * DKH + dt * 16 + lr] =
                (bf16)(oacc[dt][r] * inv);
    }
}

// ---------------------------------------------------------------- launch
extern "C" void kernel_launch(void* const* d_in, const int* in_sizes, int n_in,
                              void* d_out, int out_size, void* d_ws, size_t ws_size,
                              hipStream_t stream)
{
    const float* x  = (const float*)d_in[0];
    const float* Wq = (const float*)d_in[2];
    const float* bq = (const float*)d_in[3];
    const float* Wk = (const float*)d_in[4];
    const float* bk = (const float*)d_in[5];
    const float* Wv = (const float*)d_in[6];
    const float* bv = (const float*)d_in[7];
    const float* Wo = (const float*)d_in[8];
    const float* bo = (const float*)d_in[9];

    char* ws = (char*)d_ws;
    bf16* xb   = (bf16*)(ws);                   // 8 MB
    bf16* QKV  = (bf16*)(ws + (8u  << 20));     // 24 MB (Q,K live)
    bf16* VT   = (bf16*)(ws + (32u << 20));     // 8 MB V^T (GEMM-written)
    bf16* O    = (bf16*)(ws + (40u << 20));     // 8 MB (hosts QKV bias pre-flash)
    bf16* WT   = (bf16*)(ws + (48u << 20));     // 8 MB
    float* wsBias = (float*)O;                  // 12 KB; dead once flash writes O

    prologue<<<8204, 256, 0, stream>>>(x, Wq, Wk, Wv, Wo, bq, bk, bv,
                                       xb, WT, wsBias);

    // QKV projection; V columns go straight to VT (transposed)
    gemm_bias_kernel<bf16><<<dim3(NQKV / 128, 32), 256, 0, stream>>>(
        xb, WT, wsBias, QKV, NQKV, VT);

    flash_attn<<<dim3(TSEQ / 128, NHEAD, BATCH), 512, 0, stream>>>(QKV, VT, O);

    // out projection (bias applied directly; no split-K)
    gemm_bias_kernel<float><<<dim3(DMODEL / 128, 32), 256, 0, stream>>>(
        O, WT + 3u * (1u << 20), bo, (float*)d_out, DMODEL, nullptr);
}